// Round 2
// baseline (413.093 us; speedup 1.0000x reference)
//
#include <hip/hip_runtime.h>

// Locally-connected 3D conv with flipout perturbation (MI355X / gfx950).
// v2: one wave per SPATIAL location (covers all F=8 filters x B=4 batches).
//   lane = fo*8 + g  (fo = filter 0..7, g = tap-group 0..7)
//   Each lane processes float4 weight chunks c = g + 8j, j = 0..6 (54 chunks total).
//   W loads: 8 contiguous 128B segments per instruction (coalesced, no LDS).
//   x gathers: 8 distinct float4 addrs per instruction (fo-duplicates merge).
//   Reduction: 3-step XOR butterfly over g (24 shuffles per 32 outputs).

constexpr int B = 4, IX = 32, IY = 32, IZ = 16, CIN = 8;
constexpr int KX = 3, KY = 3, KZ = 3, F = 8;
constexpr int OX = IX - KX + 1;   // 30
constexpr int OY = IY - KY + 1;   // 30
constexpr int OZ = IZ - KZ + 1;   // 14
constexpr int IN_SIZE  = IX * IY * IZ * CIN;  // 131072
constexpr int OUT_SIZE = OX * OY * OZ * F;    // 100800
constexpr int TAPS = KX * KY * KZ * CIN;      // 216
constexpr int NSPAT = OX * OY * OZ;           // 12600
constexpr int WROW = F * TAPS;                // 1728 floats per spatial location

__global__ __launch_bounds__(256, 4) void lc3d_flipout_v2(
    const float* __restrict__ x,        // [B, IN_SIZE]
    const float* __restrict__ kmean,    // [NNZ]
    const float* __restrict__ kstd,     // [NNZ]
    const float* __restrict__ bias,     // [OUT_SIZE]
    const float* __restrict__ eps,      // [NNZ]
    const float* __restrict__ sgn_in,   // [B, IN_SIZE]
    const float* __restrict__ sgn_out,  // [B, OUT_SIZE]
    float* __restrict__ out)            // [B, OUT_SIZE]
{
    // bijective XCD swizzle (m204): nwg = 3150, q = 393, r = 6
    const int nwg = (NSPAT * 64) / 256;         // 3150
    const int q = nwg / 8, r = nwg % 8;
    const int xcd = blockIdx.x % 8, idx = blockIdx.x / 8;
    const int bid = (xcd < r ? xcd * (q + 1) : r * (q + 1) + (xcd - r) * q) + idx;

    const int wid  = (bid * 256 + (int)threadIdx.x) >> 6;  // wave id = spatial loc
    const int lane = threadIdx.x & 63;
    const int fo = lane >> 3;        // filter 0..7
    const int g  = lane & 7;         // tap group 0..7
    const int sp = wid;              // spatial location 0..12599
    if (sp >= NSPAT) return;

    const int oz = sp % OZ;
    const int t2 = sp / OZ;
    const int oy = t2 % OY;
    const int ox = t2 / OY;
    const int obase = sp * F;        // first output row of this location

    float ms[4] = {0.f, 0.f, 0.f, 0.f};   // mean-path per batch
    float ps[4] = {0.f, 0.f, 0.f, 0.f};   // perturbation per batch

    const int wbase = sp * WROW + fo * TAPS;   // float index of this lane's W row

#pragma unroll
    for (int j = 0; j < 7; ++j) {
        const int c = g + 8 * j;               // float4 chunk 0..53
        if (c < 54) {
            const int s   = c >> 1;            // spatial tap 0..26
            const int ci0 = (c & 1) << 2;      // ci 0..3 or 4..7
            const int kz  = s % KZ;
            const int sy  = s / KZ;
            const int ky  = sy % KY;
            const int kx  = sy / KY;
            const int col = (((ox + kx) * IY + (oy + ky)) * IZ + (oz + kz)) * CIN + ci0;
            const int nb  = wbase + (c << 2);  // 16B-aligned float index

            const float4 m4 = *reinterpret_cast<const float4*>(kmean + nb);
            const float4 s4 = *reinterpret_cast<const float4*>(kstd  + nb);
            const float4 e4 = *reinterpret_cast<const float4*>(eps   + nb);
            float4 se;
            se.x = s4.x * e4.x; se.y = s4.y * e4.y;
            se.z = s4.z * e4.z; se.w = s4.w * e4.w;

#pragma unroll
            for (int b = 0; b < B; ++b) {
                const float4 x4 = *reinterpret_cast<const float4*>(x      + b * IN_SIZE + col);
                const float4 si = *reinterpret_cast<const float4*>(sgn_in + b * IN_SIZE + col);
                ms[b] += m4.x * x4.x + m4.y * x4.y + m4.z * x4.z + m4.w * x4.w;
                ps[b] += se.x * (x4.x * si.x) + se.y * (x4.y * si.y)
                       + se.z * (x4.z * si.z) + se.w * (x4.w * si.w);
            }
        }
    }

    // butterfly reduce over g (lane bits 0..2): 3 steps x 8 accumulators
#pragma unroll
    for (int m = 1; m <= 4; m <<= 1) {
#pragma unroll
        for (int b = 0; b < B; ++b) {
            ms[b] += __shfl_xor(ms[b], m, 64);
            ps[b] += __shfl_xor(ps[b], m, 64);
        }
    }

    // epilogue: lanes g=0..3 write batch g for filter fo (32 outputs/wave)
    if (g < B) {
        // static-index selects (rule #20: no runtime-indexed register array)
        const float m = (g == 0) ? ms[0] : (g == 1) ? ms[1] : (g == 2) ? ms[2] : ms[3];
        const float p = (g == 0) ? ps[0] : (g == 1) ? ps[1] : (g == 2) ? ps[2] : ps[3];
        const int o = obase + fo;
        out[g * OUT_SIZE + o] = m + sgn_out[g * OUT_SIZE + o] * p + bias[o];
    }
}

extern "C" void kernel_launch(void* const* d_in, const int* in_sizes, int n_in,
                              void* d_out, int out_size, void* d_ws, size_t ws_size,
                              hipStream_t stream) {
    const float* x       = (const float*)d_in[0];
    const float* kmean   = (const float*)d_in[1];
    const float* kstd    = (const float*)d_in[2];
    const float* bias    = (const float*)d_in[3];
    const float* eps     = (const float*)d_in[4];
    const float* sgn_in  = (const float*)d_in[5];
    const float* sgn_out = (const float*)d_in[6];
    // d_in[7] = rows, d_in[8] = cols : unused (indices computed analytically)
    float* out = (float*)d_out;

    const int threads = 256;                       // 4 waves/block
    const int blocks  = (NSPAT * 64) / threads;    // 3150 (exact)

    hipLaunchKernelGGL(lc3d_flipout_v2, dim3(blocks), dim3(threads), 0, stream,
                       x, kmean, kstd, bias, eps, sgn_in, sgn_out, out);
}

// Round 3
// 353.359 us; speedup vs baseline: 1.1690x; 1.1690x over previous
//
#include <hip/hip_runtime.h>

// Locally-connected 3D conv with flipout perturbation (MI355X / gfx950).
// v3: v2 decomposition (one wave per spatial location) + spill elimination.
//   lane = fo*8 + g  (fo = filter 0..7, g = tap-group 0..7)
//   Lane processes float4 weight chunks c = g + 8j: uniform j=0..5, tail c=48+g (g<6).
//   W loads: 8 contiguous 128B segments per instruction (coalesced).
//   x gathers: 8 distinct float4 addrs per instruction (fo-duplicates merge in TA).
//   Reduction: 3-step XOR butterfly over g.
//   NAMED scalar accumulators (no register arrays -> no scratch; R2 post-mortem:
//   ms[4]/ps[4] arrays were spilled/filled every iteration = 280 MB HBM traffic).

constexpr int B = 4, IX = 32, IY = 32, IZ = 16, CIN = 8;
constexpr int KX = 3, KY = 3, KZ = 3, F = 8;
constexpr int OX = IX - KX + 1;   // 30
constexpr int OY = IY - KY + 1;   // 30
constexpr int OZ = IZ - KZ + 1;   // 14
constexpr int IN_SIZE  = IX * IY * IZ * CIN;  // 131072
constexpr int OUT_SIZE = OX * OY * OZ * F;    // 100800
constexpr int TAPS = KX * KY * KZ * CIN;      // 216
constexpr int NSPAT = OX * OY * OZ;           // 12600
constexpr int WROW = F * TAPS;                // 1728 floats per spatial location

__global__ __launch_bounds__(256) void lc3d_flipout_v3(
    const float* __restrict__ x,        // [B, IN_SIZE]
    const float* __restrict__ kmean,    // [NNZ]
    const float* __restrict__ kstd,     // [NNZ]
    const float* __restrict__ bias,     // [OUT_SIZE]
    const float* __restrict__ eps,      // [NNZ]
    const float* __restrict__ sgn_in,   // [B, IN_SIZE]
    const float* __restrict__ sgn_out,  // [B, OUT_SIZE]
    float* __restrict__ out)            // [B, OUT_SIZE]
{
    // bijective XCD swizzle (m204): nwg = 3150, q = 393, r = 6
    constexpr int nwg = (NSPAT * 64) / 256;     // 3150
    constexpr int q = nwg / 8, r = nwg % 8;
    const int xcd = blockIdx.x % 8, idx = blockIdx.x / 8;
    const int bid = (xcd < r ? xcd * (q + 1) : r * (q + 1) + (xcd - r) * q) + idx;

    const int lane = threadIdx.x & 63;
    const int fo = lane >> 3;        // filter 0..7
    const int g  = lane & 7;         // tap group 0..7
    const int sp = (bid * 256 + (int)threadIdx.x) >> 6;   // spatial loc 0..12599
    if (sp >= NSPAT) return;

    const int oz = sp % OZ;
    const int t2 = sp / OZ;
    const int oy = t2 % OY;
    const int ox = t2 / OY;

    float ms0 = 0.f, ms1 = 0.f, ms2 = 0.f, ms3 = 0.f;  // mean-path per batch
    float ps0 = 0.f, ps1 = 0.f, ps2 = 0.f, ps3 = 0.f;  // perturbation per batch

    const float* wm = kmean + sp * WROW + fo * TAPS;   // this lane's W row (16B-aligned)
    const float* ws = kstd  + sp * WROW + fo * TAPS;
    const float* we = eps   + sp * WROW + fo * TAPS;

#define DO_CHUNK(c_)                                                                  \
    {                                                                                 \
        const int cc  = (c_);                                                         \
        const int s   = cc >> 1;            /* spatial tap 0..26 */                   \
        const int ci0 = (cc & 1) << 2;      /* ci 0..3 or 4..7 */                     \
        const int kz  = s % KZ;                                                       \
        const int sy  = s / KZ;                                                       \
        const int ky  = sy % KY;                                                      \
        const int kx  = sy / KY;                                                      \
        const int col = (((ox + kx) * IY + (oy + ky)) * IZ + (oz + kz)) * CIN + ci0;  \
        const float4 m4 = *reinterpret_cast<const float4*>(wm + (cc << 2));           \
        const float4 s4 = *reinterpret_cast<const float4*>(ws + (cc << 2));           \
        const float4 e4 = *reinterpret_cast<const float4*>(we + (cc << 2));           \
        const float sex = s4.x * e4.x, sey = s4.y * e4.y;                             \
        const float sez = s4.z * e4.z, sew = s4.w * e4.w;                             \
        {   const float4 x4 = *reinterpret_cast<const float4*>(x      + 0 * IN_SIZE + col);  \
            const float4 si = *reinterpret_cast<const float4*>(sgn_in + 0 * IN_SIZE + col);  \
            ms0 += m4.x * x4.x + m4.y * x4.y + m4.z * x4.z + m4.w * x4.w;             \
            ps0 += sex * (x4.x * si.x) + sey * (x4.y * si.y)                          \
                 + sez * (x4.z * si.z) + sew * (x4.w * si.w); }                       \
        {   const float4 x4 = *reinterpret_cast<const float4*>(x      + 1 * IN_SIZE + col);  \
            const float4 si = *reinterpret_cast<const float4*>(sgn_in + 1 * IN_SIZE + col);  \
            ms1 += m4.x * x4.x + m4.y * x4.y + m4.z * x4.z + m4.w * x4.w;             \
            ps1 += sex * (x4.x * si.x) + sey * (x4.y * si.y)                          \
                 + sez * (x4.z * si.z) + sew * (x4.w * si.w); }                       \
        {   const float4 x4 = *reinterpret_cast<const float4*>(x      + 2 * IN_SIZE + col);  \
            const float4 si = *reinterpret_cast<const float4*>(sgn_in + 2 * IN_SIZE + col);  \
            ms2 += m4.x * x4.x + m4.y * x4.y + m4.z * x4.z + m4.w * x4.w;             \
            ps2 += sex * (x4.x * si.x) + sey * (x4.y * si.y)                          \
                 + sez * (x4.z * si.z) + sew * (x4.w * si.w); }                       \
        {   const float4 x4 = *reinterpret_cast<const float4*>(x      + 3 * IN_SIZE + col);  \
            const float4 si = *reinterpret_cast<const float4*>(sgn_in + 3 * IN_SIZE + col);  \
            ms3 += m4.x * x4.x + m4.y * x4.y + m4.z * x4.z + m4.w * x4.w;             \
            ps3 += sex * (x4.x * si.x) + sey * (x4.y * si.y)                          \
                 + sez * (x4.z * si.z) + sew * (x4.w * si.w); }                       \
    }

    // uniform main loop: chunks c = g + 8j, j = 0..5 (all < 48, all lanes active)
#pragma unroll 2
    for (int j = 0; j < 6; ++j) {
        DO_CHUNK(g + 8 * j);
    }
    // tail: chunks 48..53 (lanes g<6 only)
    if (g < 6) {
        DO_CHUNK(48 + g);
    }
#undef DO_CHUNK

    // butterfly reduce over g (lane bits 0..2)
#pragma unroll
    for (int m = 1; m <= 4; m <<= 1) {
        ms0 += __shfl_xor(ms0, m, 64);
        ms1 += __shfl_xor(ms1, m, 64);
        ms2 += __shfl_xor(ms2, m, 64);
        ms3 += __shfl_xor(ms3, m, 64);
        ps0 += __shfl_xor(ps0, m, 64);
        ps1 += __shfl_xor(ps1, m, 64);
        ps2 += __shfl_xor(ps2, m, 64);
        ps3 += __shfl_xor(ps3, m, 64);
    }

    // epilogue: lanes g=0..3 write batch g for filter fo (32 outputs/wave)
    if (g < B) {
        const float m = (g == 0) ? ms0 : (g == 1) ? ms1 : (g == 2) ? ms2 : ms3;
        const float p = (g == 0) ? ps0 : (g == 1) ? ps1 : (g == 2) ? ps2 : ps3;
        const int o = sp * F + fo;
        out[g * OUT_SIZE + o] = m + sgn_out[g * OUT_SIZE + o] * p + bias[o];
    }
}

extern "C" void kernel_launch(void* const* d_in, const int* in_sizes, int n_in,
                              void* d_out, int out_size, void* d_ws, size_t ws_size,
                              hipStream_t stream) {
    const float* x       = (const float*)d_in[0];
    const float* kmean   = (const float*)d_in[1];
    const float* kstd    = (const float*)d_in[2];
    const float* bias    = (const float*)d_in[3];
    const float* eps     = (const float*)d_in[4];
    const float* sgn_in  = (const float*)d_in[5];
    const float* sgn_out = (const float*)d_in[6];
    // d_in[7] = rows, d_in[8] = cols : unused (indices computed analytically)
    float* out = (float*)d_out;

    const int threads = 256;                       // 4 waves/block
    const int blocks  = (NSPAT * 64) / threads;    // 3150 (exact)

    hipLaunchKernelGGL(lc3d_flipout_v3, dim3(blocks), dim3(threads), 0, stream,
                       x, kmean, kstd, bias, eps, sgn_in, sgn_out, out);
}